// Round 16
// baseline (1412.950 us; speedup 1.0000x reference)
//
#include <hip/hip_runtime.h>
#include <math.h>
#include <stdint.h>

namespace {
constexpr int INN   = 512;          // visible rows: act[:512] == x always
constexpr int LAY   = 2048;
constexpr int DYN   = LAY - INN;    // 1536 dynamic elements act[512..2048)
constexpr int NITER = 512;
constexpr int NBLK  = 32;           // halved: fewer skew sources, half the pollers
constexpr int TPB   = 512;          // 8 waves
constexpr int WVS   = TPB / 64;     // 8
constexpr int RPW   = 6;            // rows per wave (per-wave shape unchanged)
constexpr int RPB   = WVS * RPW;    // 48 rows/block; 32*48 = 1536
constexpr int KC    = DYN / 64;     // 24 dynamic k-chunks per lane
constexpr int KX    = INN / 64;     // 8 x-col k-chunks (precomputed)
constexpr int EPT   = DYN / TPB;    // 3 polled elements per thread
constexpr float EPS = 1e-12f;

__device__ __forceinline__ uint64_t packtag(float v, uint32_t tag) {
  union { float f; uint32_t u; } c; c.f = v;
  return (uint64_t)c.u | ((uint64_t)tag << 32);
}
__device__ __forceinline__ float val_of(uint64_t p) {
  union { uint32_t u; float f; } c; c.u = (uint32_t)p; return c.f;
}
// Proven store medium (R2..R13, absmax 0.0): agent-scope UC.
__device__ __forceinline__ void ag_store64(uint64_t* p, uint64_t v) {
  __hip_atomic_store(p, v, __ATOMIC_RELAXED, __HIP_MEMORY_SCOPE_AGENT);
}

// Issue 3 UC poll loads: elements tid, tid+512, tid+1024 via THREE separate
// pointers (R14 lesson: 4096 exceeds the 13-bit signed imm, max +4095).
// Strided tid+512j layout = 512B lane-coalesced per instruction (R10-proven).
#define ISSUE3(P0, P1, P2, A0, A1, A2)                                     \
  asm volatile(                                                            \
      "global_load_dwordx2 %0, %3, off sc0 sc1\n\t"                        \
      "global_load_dwordx2 %1, %4, off sc0 sc1\n\t"                        \
      "global_load_dwordx2 %2, %5, off sc0 sc1"                            \
      : "=&v"(A0), "=&v"(A1), "=&v"(A2)                                    \
      : "v"(P0), "v"(P1), "v"(P2)                                          \
      : "memory")

// Counted wait: oldest 3 of 6 outstanding complete (vmcnt FIFO, m135).
// "+v" operands fence the compiler from hoisting uses (rule #18).
#define WAIT3(A0, A1, A2)                                                  \
  asm volatile("s_waitcnt vmcnt(3)"                                        \
               : "+v"(A0), "+v"(A1), "+v"(A2) :: "memory")

// R13 champion (1181 us, absmax 0.0), geometry only: 32 blocks x 8 waves.
// Per-wave structure byte-equivalent (6 rows, 24 k-chunks, lane-spread
// coalesced store, store-before-sync-B, A/B pipelined poll). Protocol:
// tagged 8-byte words; a block stores tag t+1 only after block-wide
// consumption of tag t (sync A), so tag t+2 stores imply all consumed t.
__global__ __launch_bounds__(TPB) void bm_tag(
    const float* __restrict__ x, const float* __restrict__ W,
    uint64_t* __restrict__ buf0, uint64_t* __restrict__ buf1,
    float* __restrict__ out) {
  __shared__ float s_act[DYN];
  __shared__ float s_red[WVS];
  const int tid = threadIdx.x;
  const int wv  = tid >> 6;
  const int ln  = tid & 63;
  const int blk = blockIdx.x;
  const int r0  = INN + blk * RPB + wv * RPW;   // this wave's 6 rows

  // ---- one-time: W[r,512:2048] into registers (6x24 = 144 regs) ----
  float w[RPW][KC];
  const float* __restrict__ Wr = W + (size_t)r0 * LAY;
#pragma unroll
  for (int r = 0; r < RPW; ++r)
#pragma unroll
    for (int i = 0; i < KC; ++i)
      w[r][i] = Wr[(size_t)r * LAY + INN + ln + 64 * i];

  // ---- one-time: c_r = W[r,:512]@x (fully reduced; added AFTER lane-reduce) ----
  float c[RPW];
  {
    float xv[KX];
#pragma unroll
    for (int i = 0; i < KX; ++i) xv[i] = x[ln + 64 * i];
#pragma unroll
    for (int r = 0; r < RPW; ++r) {
      float cc = 0.f;
#pragma unroll
      for (int i = 0; i < KX; ++i)
        cc = fmaf(Wr[(size_t)r * LAY + ln + 64 * i], xv[i], cc);
#pragma unroll
      for (int o = 1; o < 64; o <<= 1) cc += __shfl_xor(cc, o, 64);
      c[r] = cc;
    }
  }

  // ---- bootstrap: act(1) = relu(c_r), tag 1 -> buf1; lane r stores row r ----
  {
    float cv = c[0];
    cv = (ln == 1) ? c[1] : cv;
    cv = (ln == 2) ? c[2] : cv;
    cv = (ln == 3) ? c[3] : cv;
    cv = (ln == 4) ? c[4] : cv;
    cv = (ln == 5) ? c[5] : cv;
    if (ln < RPW)
      ag_store64(&buf1[r0 - INN + ln], packtag(fmaxf(cv, 0.f), 1u));
  }

  float myv[EPT];
  float inv = 0.f;
  for (int t = 1;; ++t) {
    if (t == NITER && blk != 0) return;   // non-0 blocks already stored tag 512
    uint64_t* rb = (t & 1) ? buf1 : buf0;
    const uint64_t* p0 = rb + tid;
    const uint64_t* p1 = rb + tid + 512;
    const uint64_t* p2 = rb + tid + 1024;

    // ---- pipelined poll: sets A/B alternate; check age ~= 1 RTT ----
    {
      uint64_t a0, a1, a2, b0, b1, b2;
      const uint32_t tt = (uint32_t)t;
      asm volatile("s_waitcnt vmcnt(0)" ::: "memory");  // quiesce stale set
      ISSUE3(p0, p1, p2, a0, a1, a2);
      ISSUE3(p0, p1, p2, b0, b1, b2);
      for (;;) {
        WAIT3(a0, a1, a2);                              // A done, B in flight
        if ((uint32_t)(a0 >> 32) == tt && (uint32_t)(a1 >> 32) == tt &&
            (uint32_t)(a2 >> 32) == tt) {
          myv[0] = val_of(a0); myv[1] = val_of(a1); myv[2] = val_of(a2);
          break;
        }
        ISSUE3(p0, p1, p2, a0, a1, a2);                 // reissue A
        WAIT3(b0, b1, b2);                              // B done, A in flight
        if ((uint32_t)(b0 >> 32) == tt && (uint32_t)(b1 >> 32) == tt &&
            (uint32_t)(b2 >> 32) == tt) {
          myv[0] = val_of(b0); myv[1] = val_of(b1); myv[2] = val_of(b2);
          break;
        }
        ISSUE3(p0, p1, p2, b0, b1, b2);
      }
      // one stale set may remain in flight: harmless (tag-validated; quiesced
      // by the vmcnt(0) at the next poll's start).
    }

    // ---- stage to LDS + hidden sum-of-squares (j>=1 <=> e>=512) ----
    s_act[tid]        = myv[0];
    s_act[tid + 512]  = myv[1];
    s_act[tid + 1024] = myv[2];
    float ss = fmaf(myv[1], myv[1], myv[2] * myv[2]);
#pragma unroll
    for (int o = 1; o < 64; o <<= 1) ss += __shfl_xor(ss, o, 64);
    if (ln == 0) s_red[wv] = ss;
    __syncthreads();                      // (A) poll consumed block-wide
    float sst = 0.f;
#pragma unroll
    for (int i = 0; i < WVS; ++i) sst += s_red[i];
    inv = 1.0f / fmaxf(sqrtf(sst), EPS);

    if (t == NITER) break;                // only blk 0 reaches

    // ---- matvec: y = relu(c + W[:,y-region]@a + inv * W[:,hidden]@h) ----
    float aa[RPW], bb[RPW];
#pragma unroll
    for (int r = 0; r < RPW; ++r) { aa[r] = 0.f; bb[r] = 0.f; }
#pragma unroll
    for (int i = 0; i < 8; ++i) {         // dyn cols [0,512): y-region
      const float a = s_act[ln + 64 * i];
#pragma unroll
      for (int r = 0; r < RPW; ++r) aa[r] = fmaf(w[r][i], a, aa[r]);
    }
#pragma unroll
    for (int i = 8; i < KC; ++i) {        // dyn cols [512,1536): hidden
      const float a = s_act[ln + 64 * i];
#pragma unroll
      for (int r = 0; r < RPW; ++r) bb[r] = fmaf(w[r][i], a, bb[r]);
    }
    float y[RPW];
#pragma unroll
    for (int r = 0; r < RPW; ++r) y[r] = fmaf(inv, bb[r], aa[r]);
#pragma unroll
    for (int o = 1; o < 64; o <<= 1) {
#pragma unroll
      for (int r = 0; r < RPW; ++r) y[r] += __shfl_xor(y[r], o, 64);
    }
#pragma unroll
    for (int r = 0; r < RPW; ++r) y[r] = fmaxf(y[r] + c[r], 0.f);  // c AFTER reduce

    // ---- publish act(t+1) immediately (R12 win): lane r stores row r ----
    {
      float yv = y[0];
      yv = (ln == 1) ? y[1] : yv;
      yv = (ln == 2) ? y[2] : yv;
      yv = (ln == 3) ? y[3] : yv;
      yv = (ln == 4) ? y[4] : yv;
      yv = (ln == 5) ? y[5] : yv;
      if (ln < RPW) {
        uint64_t* wbuf = ((t + 1) & 1) ? buf1 : buf0;
        ag_store64(&wbuf[r0 - INN + ln], packtag(yv, (uint32_t)(t + 1)));
      }
    }
    __syncthreads();                      // (B) WAR: s_act reads done before restage
  }

  // ---- blk 0: final output (hidden part normalized) ----
  out[tid] = x[tid];                      // TPB == 512 covers all of x
#pragma unroll
  for (int j = 0; j < EPT; ++j)
    out[INN + tid + 512 * j] = (j == 0) ? myv[j] : myv[j] * inv;
}
} // namespace

extern "C" void kernel_launch(void* const* d_in, const int* in_sizes, int n_in,
                              void* d_out, int out_size, void* d_ws, size_t ws_size,
                              hipStream_t stream) {
  const float* x = (const float*)d_in[0];
  // d_in[1] (y) only enters the reference as zeros_like -> unused.
  const float* W = (const float*)d_in[2];
  float* out = (float*)d_out;

  uint64_t* buf0 = (uint64_t*)d_ws;
  uint64_t* buf1 = buf0 + DYN;

  // Invalidate stale tags (0xFFFFFFFF matches no t in 1..512) — needed on the
  // first call and between graph replays (harness does not re-poison d_ws).
  hipMemsetAsync(d_ws, 0xFF, (size_t)2 * DYN * sizeof(uint64_t), stream);

  bm_tag<<<dim3(NBLK), dim3(TPB), 0, stream>>>(x, W, buf0, buf1, out);
}

// Round 17
// 1187.800 us; speedup vs baseline: 1.1896x; 1.1896x over previous
//
#include <hip/hip_runtime.h>
#include <math.h>
#include <stdint.h>

namespace {
constexpr int INN   = 512;          // visible rows: act[:512] == x always
constexpr int LAY   = 2048;
constexpr int DYN   = LAY - INN;    // 1536 dynamic elements act[512..2048)
constexpr int NITER = 512;
constexpr int NBLK  = 64;
constexpr int TPB   = 256;          // 4 waves (R15 lesson: 8-wave blocks regress)
constexpr int WVS   = TPB / 64;     // 4
constexpr int RPW   = 6;            // rows per wave
constexpr int RPB   = WVS * RPW;    // 24 rows/block; 64*24 = 1536
constexpr int KC    = DYN / 64;     // 24 dynamic k-chunks per lane
constexpr int KX    = INN / 64;     // 8 x-col k-chunks (precomputed)
constexpr int EPT   = DYN / TPB;    // 6 polled elements per thread
constexpr float EPS = 1e-12f;

__device__ __forceinline__ uint64_t packtag(float v, uint32_t tag) {
  union { float f; uint32_t u; } c; c.f = v;
  return (uint64_t)c.u | ((uint64_t)tag << 32);
}
__device__ __forceinline__ float val_of(uint64_t p) {
  union { uint32_t u; float f; } c; c.u = (uint32_t)p; return c.f;
}
// Proven store medium (R2..R13, absmax 0.0): agent-scope UC, HBM-backed.
__device__ __forceinline__ void ag_store64(uint64_t* p, uint64_t v) {
  __hip_atomic_store(p, v, __ATOMIC_RELAXED, __HIP_MEMORY_SCOPE_AGENT);
}

// Issue 6 UC poll loads (strided tid+256j layout = 512B lane-coalesced per
// instruction, the R10-proven pattern; offset:2048 fits the 13-bit signed
// imm, R14 lesson). No waitcnt here — counted wait comes separately.
#define ISSUE6(P0, P1, P2, A0, A1, A2, A3, A4, A5)                         \
  asm volatile(                                                            \
      "global_load_dwordx2 %0, %6, off sc0 sc1\n\t"                        \
      "global_load_dwordx2 %1, %6, off offset:2048 sc0 sc1\n\t"            \
      "global_load_dwordx2 %2, %7, off sc0 sc1\n\t"                        \
      "global_load_dwordx2 %3, %7, off offset:2048 sc0 sc1\n\t"            \
      "global_load_dwordx2 %4, %8, off sc0 sc1\n\t"                        \
      "global_load_dwordx2 %5, %8, off offset:2048 sc0 sc1"                \
      : "=&v"(A0), "=&v"(A1), "=&v"(A2), "=&v"(A3), "=&v"(A4), "=&v"(A5)   \
      : "v"(P0), "v"(P1), "v"(P2)                                          \
      : "memory")

// Counted wait: oldest 6 of 12 outstanding complete (vmcnt FIFO, m135).
// "+v" operands fence the compiler from hoisting uses (rule #18).
#define WAIT6(A0, A1, A2, A3, A4, A5)                                      \
  asm volatile("s_waitcnt vmcnt(6)"                                        \
               : "+v"(A0), "+v"(A1), "+v"(A2), "+v"(A3), "+v"(A4), "+v"(A5)\
               :: "memory")

// R13 champion restored verbatim (1181 us, absmax 0.0). Wins stacked:
// R10 lane-spread coalesced store; R12 store-before-sync-B; R13 A/B
// software-pipelined poll (checks on ~1-RTT-old data). Protocol: tagged
// (value,iter) 8-byte words; a block stores tag t+1 only after block-wide
// consumption of tag t (sync A), so tag t+2 stores imply all consumed t.
__global__ __launch_bounds__(TPB) void bm_tag(
    const float* __restrict__ x, const float* __restrict__ W,
    uint64_t* __restrict__ buf0, uint64_t* __restrict__ buf1,
    float* __restrict__ out) {
  __shared__ float s_act[DYN];
  __shared__ float s_red[WVS];
  const int tid = threadIdx.x;
  const int wv  = tid >> 6;
  const int ln  = tid & 63;
  const int blk = blockIdx.x;
  const int r0  = INN + blk * RPB + wv * RPW;   // this wave's 6 rows

  // ---- one-time: W[r,512:2048] into registers (6x24 = 144 regs) ----
  float w[RPW][KC];
  const float* __restrict__ Wr = W + (size_t)r0 * LAY;
#pragma unroll
  for (int r = 0; r < RPW; ++r)
#pragma unroll
    for (int i = 0; i < KC; ++i)
      w[r][i] = Wr[(size_t)r * LAY + INN + ln + 64 * i];

  // ---- one-time: c_r = W[r,:512]@x (fully reduced; added AFTER lane-reduce) ----
  float c[RPW];
  {
    float xv[KX];
#pragma unroll
    for (int i = 0; i < KX; ++i) xv[i] = x[ln + 64 * i];
#pragma unroll
    for (int r = 0; r < RPW; ++r) {
      float cc = 0.f;
#pragma unroll
      for (int i = 0; i < KX; ++i)
        cc = fmaf(Wr[(size_t)r * LAY + ln + 64 * i], xv[i], cc);
#pragma unroll
      for (int o = 1; o < 64; o <<= 1) cc += __shfl_xor(cc, o, 64);
      c[r] = cc;
    }
  }

  // ---- bootstrap: act(1) = relu(c_r), tag 1 -> buf1; lane r stores row r ----
  {
    float cv = c[0];
    cv = (ln == 1) ? c[1] : cv;
    cv = (ln == 2) ? c[2] : cv;
    cv = (ln == 3) ? c[3] : cv;
    cv = (ln == 4) ? c[4] : cv;
    cv = (ln == 5) ? c[5] : cv;
    if (ln < RPW)
      ag_store64(&buf1[r0 - INN + ln], packtag(fmaxf(cv, 0.f), 1u));
  }

  float myv[EPT];
  float inv = 0.f;
  for (int t = 1;; ++t) {
    if (t == NITER && blk != 0) return;   // non-0 blocks already stored tag 512
    uint64_t* rb = (t & 1) ? buf1 : buf0;
    const uint64_t* p0 = rb + tid;
    const uint64_t* p1 = rb + tid + 512;
    const uint64_t* p2 = rb + tid + 1024;

    // ---- pipelined poll: sets A/B alternate; check age ~= 1 RTT ----
    {
      uint64_t a0, a1, a2, a3, a4, a5, b0, b1, b2, b3, b4, b5;
      const uint32_t tt = (uint32_t)t;
      asm volatile("s_waitcnt vmcnt(0)" ::: "memory");  // quiesce prior leftovers
      ISSUE6(p0, p1, p2, a0, a1, a2, a3, a4, a5);
      ISSUE6(p0, p1, p2, b0, b1, b2, b3, b4, b5);
      for (;;) {
        WAIT6(a0, a1, a2, a3, a4, a5);                  // A complete, B in flight
        if ((uint32_t)(a0 >> 32) == tt && (uint32_t)(a1 >> 32) == tt &&
            (uint32_t)(a2 >> 32) == tt && (uint32_t)(a3 >> 32) == tt &&
            (uint32_t)(a4 >> 32) == tt && (uint32_t)(a5 >> 32) == tt) {
          myv[0] = val_of(a0); myv[1] = val_of(a1); myv[2] = val_of(a2);
          myv[3] = val_of(a3); myv[4] = val_of(a4); myv[5] = val_of(a5);
          break;
        }
        ISSUE6(p0, p1, p2, a0, a1, a2, a3, a4, a5);     // reissue A (12 in flight)
        WAIT6(b0, b1, b2, b3, b4, b5);                  // B complete, A in flight
        if ((uint32_t)(b0 >> 32) == tt && (uint32_t)(b1 >> 32) == tt &&
            (uint32_t)(b2 >> 32) == tt && (uint32_t)(b3 >> 32) == tt &&
            (uint32_t)(b4 >> 32) == tt && (uint32_t)(b5 >> 32) == tt) {
          myv[0] = val_of(b0); myv[1] = val_of(b1); myv[2] = val_of(b2);
          myv[3] = val_of(b3); myv[4] = val_of(b4); myv[5] = val_of(b5);
          break;
        }
        ISSUE6(p0, p1, p2, b0, b1, b2, b3, b4, b5);
      }
      // one stale set may remain in flight: harmless (tag-validated medium;
      // quiesced by the vmcnt(0) at the next poll's start).
    }

    // ---- stage to LDS + sum-of-squares of hidden part (j>=2 <=> e>=512) ----
    float ss = 0.f;
#pragma unroll
    for (int j = 0; j < EPT; ++j) {
      s_act[tid + TPB * j] = myv[j];
      if (j >= 2) ss = fmaf(myv[j], myv[j], ss);
    }
#pragma unroll
    for (int o = 1; o < 64; o <<= 1) ss += __shfl_xor(ss, o, 64);
    if (ln == 0) s_red[wv] = ss;
    __syncthreads();                      // (A) poll consumed block-wide
    inv = 1.0f / fmaxf(sqrtf(s_red[0] + s_red[1] + s_red[2] + s_red[3]), EPS);

    if (t == NITER) break;                // only blk 0 reaches

    // ---- matvec: y = relu(c + W[:,y-region]@a + inv * W[:,hidden]@h) ----
    float aa[RPW], bb[RPW];
#pragma unroll
    for (int r = 0; r < RPW; ++r) { aa[r] = 0.f; bb[r] = 0.f; }
#pragma unroll
    for (int i = 0; i < 8; ++i) {         // dyn cols [0,512): y-region
      const float a = s_act[ln + 64 * i];
#pragma unroll
      for (int r = 0; r < RPW; ++r) aa[r] = fmaf(w[r][i], a, aa[r]);
    }
#pragma unroll
    for (int i = 8; i < KC; ++i) {        // dyn cols [512,1536): hidden
      const float a = s_act[ln + 64 * i];
#pragma unroll
      for (int r = 0; r < RPW; ++r) bb[r] = fmaf(w[r][i], a, bb[r]);
    }
    float y[RPW];
#pragma unroll
    for (int r = 0; r < RPW; ++r) y[r] = fmaf(inv, bb[r], aa[r]);
#pragma unroll
    for (int o = 1; o < 64; o <<= 1) {
#pragma unroll
      for (int r = 0; r < RPW; ++r) y[r] += __shfl_xor(y[r], o, 64);
    }
#pragma unroll
    for (int r = 0; r < RPW; ++r) y[r] = fmaxf(y[r] + c[r], 0.f);  // c AFTER reduce

    // ---- publish act(t+1) immediately (R12 win): lane r stores row r ----
    {
      float yv = y[0];
      yv = (ln == 1) ? y[1] : yv;
      yv = (ln == 2) ? y[2] : yv;
      yv = (ln == 3) ? y[3] : yv;
      yv = (ln == 4) ? y[4] : yv;
      yv = (ln == 5) ? y[5] : yv;
      if (ln < RPW) {
        uint64_t* wbuf = ((t + 1) & 1) ? buf1 : buf0;
        ag_store64(&wbuf[r0 - INN + ln], packtag(yv, (uint32_t)(t + 1)));
      }
    }
    __syncthreads();                      // (B) WAR: s_act reads done before restage
  }

  // ---- blk 0: final output (hidden part normalized) ----
  out[tid]       = x[tid];
  out[tid + TPB] = x[tid + TPB];
#pragma unroll
  for (int j = 0; j < EPT; ++j)
    out[INN + tid + TPB * j] = (j < 2) ? myv[j] : myv[j] * inv;
}
} // namespace

extern "C" void kernel_launch(void* const* d_in, const int* in_sizes, int n_in,
                              void* d_out, int out_size, void* d_ws, size_t ws_size,
                              hipStream_t stream) {
  const float* x = (const float*)d_in[0];
  // d_in[1] (y) only enters the reference as zeros_like -> unused.
  const float* W = (const float*)d_in[2];
  float* out = (float*)d_out;

  uint64_t* buf0 = (uint64_t*)d_ws;
  uint64_t* buf1 = buf0 + DYN;

  // Invalidate stale tags (0xFFFFFFFF matches no t in 1..512) — needed on the
  // first call and between graph replays (harness does not re-poison d_ws).
  hipMemsetAsync(d_ws, 0xFF, (size_t)2 * DYN * sizeof(uint64_t), stream);

  bm_tag<<<dim3(NBLK), dim3(TPB), 0, stream>>>(x, W, buf0, buf1, out);
}